// Round 1
// baseline (59261.090 us; speedup 1.0000x reference)
//
#include <hip/hip_runtime.h>
#include <stdint.h>

// ---------------------------------------------------------------------------
// ComplexApproximateBNN: T=128 recurrent steps, each:
//   h1 = act(concat(h0_t, bp) @ Wh0^T + bh0)
//   h2 = act(concat(h1, li)  @ Wh1^T + bh1);  li' = l2norm(h2)
//   h3 = act(concat(h2, h1)  @ Wh2^T + bh2)
//   h4 = act(concat(h3, h2)  @ Wh3^T + bh3);  bp' = l2norm(h4)
//   y  = act(h4 @ Wout^T + bout)
// h0 has no recurrent dep -> precomputed for all (b,t) in one big GEMM.
// All matmuls bf16 MFMA 16x16x32, fp32 accumulate. Weights kept in original
// [n][k] row-major layout (== MFMA B-operand layout, no transpose needed).
// ---------------------------------------------------------------------------

typedef __bf16 bf16;
typedef __attribute__((ext_vector_type(8))) __bf16 bf16x8;
typedef __attribute__((ext_vector_type(4))) float f32x4;

#define BATCH 64
#define TSTEPS 128
#define INDIM 512
#define XDIM 2048
#define OUTDIM 256

__device__ __forceinline__ float apply_act(float h, int id) {
  switch (id) {
    case 0: return fmaxf(h, 0.0f);                       // relu
    case 1: return 1.0f / (1.0f + __expf(-h));           // sigmoid
    case 2: return tanhf(h);                             // tanh
    case 3: return h >= 0.0f ? h : 0.1f * h;             // leaky 0.1
    default: {                                           // selu
      const float sc = 1.0507009873554805f;
      const float al = 1.6732632423543772f;
      return h > 0.0f ? sc * h : sc * al * (__expf(h) - 1.0f);
    }
  }
}

// MODE 0: out = bf16 [64][N] (step hidden layers)
// MODE 1: out = bf16 h0 buffer [T][B][N], input rows r = b*128+t (remap)
// MODE 2: out = float d_out [B][T][256], aux = t
template <int MODE>
__global__ __launch_bounds__(256) void gemm_act(
    const bf16* __restrict__ A1, const bf16* __restrict__ A2,
    const bf16* __restrict__ W, const float* __restrict__ bias,
    const int* __restrict__ acts, void* __restrict__ outp,
    int K1, int KTOT, int N, int aux) {
  const int tid = threadIdx.x;
  const int lane = tid & 63;
  const int wv = tid >> 6;
  const int wm = (wv & 1) * 32;   // wave m-offset within 64-row tile
  const int wn = (wv >> 1) * 64;  // wave n-offset within 128-col tile
  const int nblk = blockIdx.x * 128;
  const int mblk = blockIdx.y * 64;
  const int l15 = lane & 15;
  const int kb8 = (lane >> 4) * 8;

  f32x4 acc[2][4];
  const f32x4 zero = {0.f, 0.f, 0.f, 0.f};
#pragma unroll
  for (int i = 0; i < 2; i++)
#pragma unroll
    for (int j = 0; j < 4; j++) acc[i][j] = zero;

  const int K2 = KTOT - K1;
  for (int kt = 0; kt < KTOT; kt += 32) {
    const bf16* As;
    int kcol, rs;
    if (kt < K1) { As = A1; kcol = kt; rs = K1; }
    else         { As = A2; kcol = kt - K1; rs = K2; }

    bf16x8 a[2], b[4];
#pragma unroll
    for (int mt = 0; mt < 2; mt++) {
      int m = mblk + wm + mt * 16 + l15;
      a[mt] = *(const bf16x8*)(As + (size_t)m * rs + kcol + kb8);
    }
#pragma unroll
    for (int nt = 0; nt < 4; nt++) {
      int n = nblk + wn + nt * 16 + l15;
      b[nt] = *(const bf16x8*)(W + (size_t)n * KTOT + kt + kb8);
    }
#pragma unroll
    for (int mt = 0; mt < 2; mt++)
#pragma unroll
      for (int nt = 0; nt < 4; nt++)
        acc[mt][nt] = __builtin_amdgcn_mfma_f32_16x16x32_bf16(a[mt], b[nt], acc[mt][nt], 0, 0, 0);
  }

  // epilogue: C/D layout col = lane&15, row = (lane>>4)*4 + reg
#pragma unroll
  for (int mt = 0; mt < 2; mt++) {
#pragma unroll
    for (int nt = 0; nt < 4; nt++) {
      int n = nblk + wn + nt * 16 + l15;
      float bv = bias[n];
      int aid = acts[n];
#pragma unroll
      for (int rr = 0; rr < 4; rr++) {
        int m = wm + mt * 16 + (lane >> 4) * 4 + rr;  // row within 64-tile
        float v = apply_act(acc[mt][nt][rr] + bv, aid);
        if (MODE == 0) {
          ((bf16*)outp)[(size_t)m * N + n] = (bf16)v;
        } else if (MODE == 1) {
          int row = mblk + m;            // = b*128 + t
          int bb = row >> 7;
          int tt = row & 127;
          ((bf16*)outp)[((size_t)tt * BATCH + bb) * N + n] = (bf16)v;
        } else {
          ((float*)outp)[((size_t)m * TSTEPS + aux) * OUTDIM + n] = v;
        }
      }
    }
  }
}

// row-l2-normalize h2 -> li (rows 0..63) and h4 -> bp (rows 64..127)
__global__ __launch_bounds__(256) void rownorm2(
    const bf16* __restrict__ h2, const bf16* __restrict__ h4,
    bf16* __restrict__ li, bf16* __restrict__ bp) {
  __shared__ float sm[256];
  const int tid = threadIdx.x;
  int r = blockIdx.x;
  const bf16* in;
  bf16* out;
  if (r < 64) { in = h2 + (size_t)r * XDIM; out = li + (size_t)r * XDIM; }
  else        { in = h4 + (size_t)(r - 64) * XDIM; out = bp + (size_t)(r - 64) * XDIM; }

  float s = 0.f;
#pragma unroll
  for (int i = 0; i < 8; i++) {
    float v = (float)in[tid + i * 256];
    s += v * v;
  }
  sm[tid] = s;
  __syncthreads();
  for (int off = 128; off > 0; off >>= 1) {
    if (tid < off) sm[tid] += sm[tid + off];
    __syncthreads();
  }
  float scale = 1.0f / fmaxf(sqrtf(sm[0]), 1e-12f);
#pragma unroll
  for (int i = 0; i < 8; i++) {
    out[tid + i * 256] = (bf16)((float)in[tid + i * 256] * scale);
  }
}

__global__ __launch_bounds__(256) void cvt_bf16(
    const float* __restrict__ in, bf16* __restrict__ out, int n4) {
  int i = blockIdx.x * 256 + threadIdx.x;
  if (i < n4) {
    float4 v = ((const float4*)in)[i];
    union { bf16 b[4]; unsigned long long u; } pk;
    pk.b[0] = (bf16)v.x;
    pk.b[1] = (bf16)v.y;
    pk.b[2] = (bf16)v.z;
    pk.b[3] = (bf16)v.w;
    ((unsigned long long*)out)[i] = pk.u;
  }
}

__global__ __launch_bounds__(256) void zero32(uint32_t* __restrict__ p, int n) {
  int i = blockIdx.x * 256 + threadIdx.x;
  if (i < n) p[i] = 0u;
}

extern "C" void kernel_launch(void* const* d_in, const int* in_sizes, int n_in,
                              void* d_out, int out_size, void* d_ws, size_t ws_size,
                              hipStream_t stream) {
  const float* x     = (const float*)d_in[0];   // [64,128,512]
  const float* W_in  = (const float*)d_in[1];   // [2048,512]
  const float* b_in  = (const float*)d_in[2];   // [2048]
  const float* W_h   = (const float*)d_in[3];   // [4,2048,4096]
  const float* b_h   = (const float*)d_in[4];   // [4,2048]
  const float* W_out = (const float*)d_in[5];   // [256,2048]
  const float* b_out = (const float*)d_in[6];   // [256]
  const int* act_ids = (const int*)d_in[7];     // [5,2048]
  const int* out_act = (const int*)d_in[8];     // [256]
  float* out = (float*)d_out;                   // [64,128,256]

  // ws layout (bf16 buffers), total ~113.8 MB
  char* w = (char*)d_ws;
  bf16* xbf   = (bf16*)w; w += (size_t)BATCH * TSTEPS * INDIM * 2;       // 8 MB
  bf16* winb  = (bf16*)w; w += (size_t)XDIM * INDIM * 2;                 // 2 MB
  bf16* whb   = (bf16*)w; w += (size_t)4 * XDIM * (2 * XDIM) * 2;        // 64 MB
  bf16* woutb = (bf16*)w; w += (size_t)OUTDIM * XDIM * 2;                // 1 MB
  bf16* h0    = (bf16*)w; w += (size_t)TSTEPS * BATCH * XDIM * 2;        // 32 MB
  bf16* h1    = (bf16*)w; w += (size_t)BATCH * XDIM * 2;
  bf16* h2    = (bf16*)w; w += (size_t)BATCH * XDIM * 2;
  bf16* h3    = (bf16*)w; w += (size_t)BATCH * XDIM * 2;
  bf16* h4    = (bf16*)w; w += (size_t)BATCH * XDIM * 2;
  bf16* bp    = (bf16*)w; w += (size_t)BATCH * XDIM * 2;
  bf16* li    = (bf16*)w; w += (size_t)BATCH * XDIM * 2;  // bp,li adjacent

  // 1) fp32 -> bf16 conversions (weights keep original [n][k] layout)
  cvt_bf16<<<4096, 256, 0, stream>>>(x, xbf, (BATCH * TSTEPS * INDIM) / 4);
  cvt_bf16<<<1024, 256, 0, stream>>>(W_in, winb, (XDIM * INDIM) / 4);
  cvt_bf16<<<32768, 256, 0, stream>>>(W_h, whb, (4 * XDIM * 2 * XDIM) / 4);
  cvt_bf16<<<512, 256, 0, stream>>>(W_out, woutb, (OUTDIM * XDIM) / 4);

  // 2) zero recurrent states bp, li (adjacent: 2*64*2048 bf16 = 131072 u32)
  zero32<<<512, 256, 0, stream>>>((uint32_t*)bp, (2 * BATCH * XDIM * 2) / 4);

  // 3) h0 for all (b,t): [8192,512] @ [512->2048], remapped to [t][b][2048]
  gemm_act<1><<<dim3(16, 128), 256, 0, stream>>>(
      xbf, xbf, winb, b_in, act_ids, h0, INDIM, INDIM, XDIM, 0);

  // 4) sequential timesteps
  const size_t wstride = (size_t)XDIM * 2 * XDIM;  // per-layer weight elems
  for (int t = 0; t < TSTEPS; t++) {
    const bf16* h0t = h0 + (size_t)t * BATCH * XDIM;
    // h1 = act(concat(h0_t, bp) @ Wh0^T + bh0)
    gemm_act<0><<<dim3(16, 1), 256, 0, stream>>>(
        h0t, bp, whb + 0 * wstride, b_h + 0 * XDIM, act_ids + 1 * XDIM,
        h1, XDIM, 2 * XDIM, XDIM, 0);
    // h2 = act(concat(h1, li) @ Wh1^T + bh1)
    gemm_act<0><<<dim3(16, 1), 256, 0, stream>>>(
        h1, li, whb + 1 * wstride, b_h + 1 * XDIM, act_ids + 2 * XDIM,
        h2, XDIM, 2 * XDIM, XDIM, 0);
    // h3 = act(concat(h2, h1) @ Wh2^T + bh2)
    gemm_act<0><<<dim3(16, 1), 256, 0, stream>>>(
        h2, h1, whb + 2 * wstride, b_h + 2 * XDIM, act_ids + 3 * XDIM,
        h3, XDIM, 2 * XDIM, XDIM, 0);
    // h4 = act(concat(h3, h2) @ Wh3^T + bh3)
    gemm_act<0><<<dim3(16, 1), 256, 0, stream>>>(
        h3, h2, whb + 3 * wstride, b_h + 3 * XDIM, act_ids + 4 * XDIM,
        h4, XDIM, 2 * XDIM, XDIM, 0);
    // li' = l2norm(h2), bp' = l2norm(h4) (consumed next step)
    rownorm2<<<128, 256, 0, stream>>>(h2, h4, li, bp);
    // y_t = act(h4 @ Wout^T + bout) -> d_out[:, t, :]
    gemm_act<2><<<dim3(2, 1), 256, 0, stream>>>(
        h4, h4, woutb, b_out, out_act, out, XDIM, XDIM, OUTDIM, t);
  }
}

// Round 2
// 10206.290 us; speedup vs baseline: 5.8063x; 5.8063x over previous
//
#include <hip/hip_runtime.h>
#include <stdint.h>

// ---------------------------------------------------------------------------
// ComplexApproximateBNN, round 2.
// Step GEMM redesign: C[64,N] = act(concat(A1,A2)[64,4096] @ W[N,4096]^T + b)
//   grid (N/16, 2): 16-col tile x 32-row half -> 256 WGs (fills 256 CUs)
//   4 waves split K: waves 0,1 -> A1 (k 0..2047), waves 2,3 -> A2 (k 2048..4095)
//   LDS reduction of 4 partials; epilogue fuses bias+act.
// l2norm fusion: producers (h2, h4) emit per-row sumsq of the fp32 activated
// values via atomicAdd into per-step slots; consumers scale ONLY the A2
// partial by 1/max(sqrt(ss),1e-12) in the epilogue (exact, since waves 2,3
// contribute only A2). Raw h2/h4 are read unscaled -> no per-k VALU cost.
// ---------------------------------------------------------------------------

typedef __bf16 bf16;
typedef __attribute__((ext_vector_type(8))) __bf16 bf16x8;
typedef __attribute__((ext_vector_type(4))) float f32x4;

#define BATCH 64
#define TSTEPS 128
#define INDIM 512
#define XDIM 2048
#define OUTDIM 256

__device__ __forceinline__ float apply_act(float h, int id) {
  switch (id) {
    case 0: return fmaxf(h, 0.0f);                       // relu
    case 1: return 1.0f / (1.0f + __expf(-h));           // sigmoid
    case 2: return tanhf(h);                             // tanh
    case 3: return h >= 0.0f ? h : 0.1f * h;             // leaky 0.1
    default: {                                           // selu
      const float sc = 1.0507009873554805f;
      const float al = 1.6732632423543772f;
      return h > 0.0f ? sc * h : sc * al * (__expf(h) - 1.0f);
    }
  }
}

// KPW: K-range per wave (1024 hidden, 512 out). HAS_A2: concat input.
// SCALE_A2: scale A2 partial by rsqrt(ss_in). EMIT_SS: atomic sumsq of act'd
// output into ss_out. MODE 0: bf16 [64][N]; MODE 1: float d_out [B][T][256].
template <int KPW, bool HAS_A2, bool SCALE_A2, bool EMIT_SS, int MODE>
__global__ __launch_bounds__(256) void step_gemm(
    const bf16* __restrict__ A1, const bf16* __restrict__ A2,
    const bf16* __restrict__ W, const float* __restrict__ bias,
    const int* __restrict__ acts, const float* __restrict__ ss_in,
    float* __restrict__ ss_out, bf16* __restrict__ outb,
    float* __restrict__ outf, int KTOT, int N, int t) {
  const int tid = threadIdx.x;
  const int lane = tid & 63;
  const int w = tid >> 6;
  const int l15 = lane & 15;
  const int kb8 = (lane >> 4) * 8;
  const int nblk = blockIdx.x * 16;
  const int mrow = blockIdx.y * 32;

  // wave's K assignment (A-source, offset within source, global k for W)
  const bf16* As;
  int koff, wk;
  if (HAS_A2) {
    As = (w >= 2) ? A2 : A1;
    koff = (w & 1) * KPW;
    wk = (w >= 2 ? 2048 : 0) + koff;
  } else {
    As = A1;
    koff = w * KPW;
    wk = koff;
  }

  const bf16* ap0 = As + (size_t)(mrow + l15) * 2048 + koff + kb8;
  const bf16* ap1 = ap0 + 16 * 2048;
  const bf16* bpw = W + (size_t)(nblk + l15) * KTOT + wk + kb8;

  f32x4 acc0 = {0.f, 0.f, 0.f, 0.f};
  f32x4 acc1 = {0.f, 0.f, 0.f, 0.f};
#pragma unroll 4
  for (int k = 0; k < KPW; k += 32) {
    bf16x8 a0 = *(const bf16x8*)(ap0 + k);
    bf16x8 a1 = *(const bf16x8*)(ap1 + k);
    bf16x8 b  = *(const bf16x8*)(bpw + k);
    acc0 = __builtin_amdgcn_mfma_f32_16x16x32_bf16(a0, b, acc0, 0, 0, 0);
    acc1 = __builtin_amdgcn_mfma_f32_16x16x32_bf16(a1, b, acc1, 0, 0, 0);
  }

  // stash partials: red[wave][row(32)][col(16)], +1 pad on cols
  __shared__ float red[4][32][17];
  const int q4 = lane >> 4;
#pragma unroll
  for (int r = 0; r < 4; r++) red[w][q4 * 4 + r][l15] = acc0[r];
#pragma unroll
  for (int r = 0; r < 4; r++) red[w][16 + q4 * 4 + r][l15] = acc1[r];
  __syncthreads();

  const int row = tid >> 3;      // 0..31
  const int c0 = (tid & 7) * 2;  // even col
  const int rg = mrow + row;     // global batch row

  float scale = 1.0f;
  if (SCALE_A2) {
    float nrm = sqrtf(ss_in[rg]);
    scale = 1.0f / fmaxf(nrm, 1e-12f);
  }

  float v[2];
#pragma unroll
  for (int j = 0; j < 2; j++) {
    int c = c0 + j;
    float lo = red[0][row][c] + red[1][row][c];
    float hi = red[2][row][c] + red[3][row][c];
    float pre = SCALE_A2 ? (lo + scale * hi) : (lo + hi);
    int n = nblk + c;
    pre += bias[n];
    v[j] = apply_act(pre, acts[n]);
  }

  if (EMIT_SS) {
    float ss = v[0] * v[0] + v[1] * v[1];
    ss += __shfl_xor(ss, 1);
    ss += __shfl_xor(ss, 2);
    ss += __shfl_xor(ss, 4);
    if ((tid & 7) == 0) atomicAdd(ss_out + rg, ss);
  }

  if (MODE == 0) {
    union { bf16 b2[2]; uint32_t u; } pk;
    pk.b2[0] = (bf16)v[0];
    pk.b2[1] = (bf16)v[1];
    *(uint32_t*)(outb + (size_t)rg * N + nblk + c0) = pk.u;
  } else {
    *(float2*)(outf + ((size_t)rg * TSTEPS + t) * OUTDIM + nblk + c0) =
        make_float2(v[0], v[1]);
  }
}

// h0 precompute: [8192,512]@[512->2048], rows r=b*128+t remapped to [t][b][n]
__global__ __launch_bounds__(256) void h0_gemm(
    const bf16* __restrict__ A, const bf16* __restrict__ W,
    const float* __restrict__ bias, const int* __restrict__ acts,
    bf16* __restrict__ outp) {
  const int tid = threadIdx.x;
  const int lane = tid & 63;
  const int wv = tid >> 6;
  const int wm = (wv & 1) * 32;
  const int wn = (wv >> 1) * 64;
  const int nblk = blockIdx.x * 128;
  const int mblk = blockIdx.y * 64;
  const int l15 = lane & 15;
  const int kb8 = (lane >> 4) * 8;

  f32x4 acc[2][4];
  const f32x4 zero = {0.f, 0.f, 0.f, 0.f};
#pragma unroll
  for (int i = 0; i < 2; i++)
#pragma unroll
    for (int j = 0; j < 4; j++) acc[i][j] = zero;

  for (int kt = 0; kt < INDIM; kt += 32) {
    bf16x8 a[2], b[4];
#pragma unroll
    for (int mt = 0; mt < 2; mt++) {
      int m = mblk + wm + mt * 16 + l15;
      a[mt] = *(const bf16x8*)(A + (size_t)m * INDIM + kt + kb8);
    }
#pragma unroll
    for (int nt = 0; nt < 4; nt++) {
      int n = nblk + wn + nt * 16 + l15;
      b[nt] = *(const bf16x8*)(W + (size_t)n * INDIM + kt + kb8);
    }
#pragma unroll
    for (int mt = 0; mt < 2; mt++)
#pragma unroll
      for (int nt = 0; nt < 4; nt++)
        acc[mt][nt] = __builtin_amdgcn_mfma_f32_16x16x32_bf16(a[mt], b[nt], acc[mt][nt], 0, 0, 0);
  }

#pragma unroll
  for (int mt = 0; mt < 2; mt++) {
#pragma unroll
    for (int nt = 0; nt < 4; nt++) {
      int n = nblk + wn + nt * 16 + l15;
      float bv = bias[n];
      int aid = acts[n];
#pragma unroll
      for (int rr = 0; rr < 4; rr++) {
        int m = wm + mt * 16 + (lane >> 4) * 4 + rr;
        float v = apply_act(acc[mt][nt][rr] + bv, aid);
        int rowg = mblk + m;  // = b*128 + t
        int bb = rowg >> 7;
        int tt = rowg & 127;
        outp[((size_t)tt * BATCH + bb) * XDIM + n] = (bf16)v;
      }
    }
  }
}

__global__ __launch_bounds__(256) void cvt_bf16(
    const float* __restrict__ in, bf16* __restrict__ out, int n4) {
  int i = blockIdx.x * 256 + threadIdx.x;
  if (i < n4) {
    float4 v = ((const float4*)in)[i];
    union { bf16 b[4]; unsigned long long u; } pk;
    pk.b[0] = (bf16)v.x;
    pk.b[1] = (bf16)v.y;
    pk.b[2] = (bf16)v.z;
    pk.b[3] = (bf16)v.w;
    ((unsigned long long*)out)[i] = pk.u;
  }
}

__global__ __launch_bounds__(256) void zero32(uint32_t* __restrict__ p, int n) {
  int i = blockIdx.x * 256 + threadIdx.x;
  if (i < n) p[i] = 0u;
}

extern "C" void kernel_launch(void* const* d_in, const int* in_sizes, int n_in,
                              void* d_out, int out_size, void* d_ws, size_t ws_size,
                              hipStream_t stream) {
  const float* x     = (const float*)d_in[0];   // [64,128,512]
  const float* W_in  = (const float*)d_in[1];   // [2048,512]
  const float* b_in  = (const float*)d_in[2];   // [2048]
  const float* W_h   = (const float*)d_in[3];   // [4,2048,4096]
  const float* b_h   = (const float*)d_in[4];   // [4,2048]
  const float* W_out = (const float*)d_in[5];   // [256,2048]
  const float* b_out = (const float*)d_in[6];   // [256]
  const int* act_ids = (const int*)d_in[7];     // [5,2048]
  const int* out_act = (const int*)d_in[8];     // [256]
  float* out = (float*)d_out;                   // [64,128,256]

  // ws layout
  char* w = (char*)d_ws;
  bf16* xbf   = (bf16*)w; w += (size_t)BATCH * TSTEPS * INDIM * 2;   // 8 MB
  bf16* winb  = (bf16*)w; w += (size_t)XDIM * INDIM * 2;             // 2 MB
  bf16* whb   = (bf16*)w; w += (size_t)4 * XDIM * (2 * XDIM) * 2;    // 64 MB
  bf16* woutb = (bf16*)w; w += (size_t)OUTDIM * XDIM * 2;            // 1 MB
  bf16* h0    = (bf16*)w; w += (size_t)TSTEPS * BATCH * XDIM * 2;    // 32 MB
  bf16* h1    = (bf16*)w; w += (size_t)BATCH * XDIM * 2;
  bf16* h3    = (bf16*)w; w += (size_t)BATCH * XDIM * 2;
  // ---- zero region start ----
  char* zstart = w;
  bf16* h2a   = (bf16*)w; w += (size_t)BATCH * XDIM * 2;   // h2 ping
  bf16* h2b   = (bf16*)w; w += (size_t)BATCH * XDIM * 2;   // h2 pong (t=0 reads)
  bf16* h4    = (bf16*)w; w += (size_t)BATCH * XDIM * 2;   // t=0 reads zeros
  float* ss_li = (float*)w; w += (size_t)(TSTEPS + 1) * BATCH * 4;  // [129][64]
  float* ss_bp = (float*)w; w += (size_t)(TSTEPS + 1) * BATCH * 4;
  int zero_u32 = (int)((w - zstart) / 4);

  // 1) fp32 -> bf16 (weights keep [n][k] layout = MFMA B-operand layout)
  cvt_bf16<<<4096, 256, 0, stream>>>(x, xbf, (BATCH * TSTEPS * INDIM) / 4);
  cvt_bf16<<<1024, 256, 0, stream>>>(W_in, winb, (XDIM * INDIM) / 4);
  cvt_bf16<<<32768, 256, 0, stream>>>(W_h, whb, (4 * XDIM * 2 * XDIM) / 4);
  cvt_bf16<<<512, 256, 0, stream>>>(W_out, woutb, (OUTDIM * XDIM) / 4);

  // 2) zero recurrent state + sumsq slots
  zero32<<<(zero_u32 + 255) / 256, 256, 0, stream>>>((uint32_t*)zstart, zero_u32);

  // 3) h0 for all (b,t)
  h0_gemm<<<dim3(16, 128), 256, 0, stream>>>(xbf, winb, b_in, act_ids, h0);

  // 4) sequential timesteps, 5 dispatches each
  const size_t wstride = (size_t)XDIM * 2 * XDIM;
  for (int t = 0; t < TSTEPS; t++) {
    const bf16* h0t = h0 + (size_t)t * BATCH * XDIM;
    bf16* h2_new = (t & 1) ? h2b : h2a;
    bf16* h2_old = (t & 1) ? h2a : h2b;

    // h1 = act([h0_t, norm(h4_prev)] @ Wh0^T + bh0)
    step_gemm<1024, true, true, false, 0><<<dim3(128, 2), 256, 0, stream>>>(
        h0t, h4, whb + 0 * wstride, b_h + 0 * XDIM, act_ids + 1 * XDIM,
        ss_bp + t * BATCH, nullptr, h1, nullptr, 4096, XDIM, t);
    // h2 = act([h1, norm(h2_prev)] @ Wh1^T + bh1); emit ss_li[t+1]
    step_gemm<1024, true, true, true, 0><<<dim3(128, 2), 256, 0, stream>>>(
        h1, h2_old, whb + 1 * wstride, b_h + 1 * XDIM, act_ids + 2 * XDIM,
        ss_li + t * BATCH, ss_li + (t + 1) * BATCH, h2_new, nullptr, 4096, XDIM, t);
    // h3 = act([h2, h1] @ Wh2^T + bh2)
    step_gemm<1024, true, false, false, 0><<<dim3(128, 2), 256, 0, stream>>>(
        h2_new, h1, whb + 2 * wstride, b_h + 2 * XDIM, act_ids + 3 * XDIM,
        nullptr, nullptr, h3, nullptr, 4096, XDIM, t);
    // h4 = act([h3, h2] @ Wh3^T + bh3); emit ss_bp[t+1]
    step_gemm<1024, true, false, true, 0><<<dim3(128, 2), 256, 0, stream>>>(
        h3, h2_new, whb + 3 * wstride, b_h + 3 * XDIM, act_ids + 4 * XDIM,
        nullptr, ss_bp + (t + 1) * BATCH, h4, nullptr, 4096, XDIM, t);
    // y_t = act(h4 @ Wout^T + bout) -> d_out[:, t, :]
    step_gemm<512, false, false, false, 1><<<dim3(16, 2), 256, 0, stream>>>(
        h4, nullptr, woutb, b_out, out_act,
        nullptr, nullptr, nullptr, out, 2048, OUTDIM, t);
  }
}